// Round 9
// baseline (384.770 us; speedup 1.0000x reference)
//
#include <hip/hip_runtime.h>
#include <hip/hip_bf16.h>

#define L_Q 49
#define D_MODEL 256
#define NHEAD 8
#define DK 32
#define PP 41
#define POS_OFF 20

typedef __attribute__((ext_vector_type(8))) __bf16 bf16x8;
typedef __attribute__((ext_vector_type(4))) float f32x4;
typedef __attribute__((ext_vector_type(8))) unsigned short u16x8;

__device__ __forceinline__ float bf2f(unsigned short u) {
    return __uint_as_float(((unsigned)u) << 16);
}
__device__ __forceinline__ unsigned short f2bf(float f) {
    unsigned u = __float_as_uint(f);
    return (unsigned short)((u + 0x7FFF + ((u >> 16) & 1)) >> 16);
}

// ---------------- one-time W conversion to bf16 (q-rows pre-scaled by `scaling`)
__global__ __launch_bounds__(256)
void convert_w(const float* __restrict__ W, const float* __restrict__ out_w,
               float scaling,
               unsigned short* __restrict__ wbf, unsigned short* __restrict__ owbf) {
    int i = blockIdx.x * 256 + threadIdx.x;   // 65536 float4 total
    if (i < 49152) {
        int row = i >> 6;                      // 64 float4 per 256-wide row
        float sc = (row < 256) ? scaling : 1.0f;
        float4 v = reinterpret_cast<const float4*>(W)[i];
        ushort4 o = { f2bf(v.x * sc), f2bf(v.y * sc), f2bf(v.z * sc), f2bf(v.w * sc) };
        reinterpret_cast<ushort4*>(wbf)[i] = o;
    } else {
        float4 v = reinterpret_cast<const float4*>(out_w)[i - 49152];
        ushort4 o = { f2bf(v.x), f2bf(v.y), f2bf(v.z), f2bf(v.w) };
        reinterpret_cast<ushort4*>(owbf)[i - 49152] = o;
    }
}

// ---------------- k_pos prep (f32 accumulate, bf16 store): kpb[which][p][d]
__global__ __launch_bounds__(256)
void prep_kpos(const float* __restrict__ pos_y, const float* __restrict__ pos_x,
               const float* __restrict__ W, unsigned short* __restrict__ kpb) {
    int p = blockIdx.x;          // 0..40
    int which = blockIdx.y;      // 0=y, 1=x
    __shared__ float pr[128];
    int d = threadIdx.x;         // 0..255
    if (d < 128) pr[d] = which ? pos_x[p * 128 + d] : pos_y[p * 128 + d];
    __syncthreads();
    const float* Wk = W + 256 * 256;  // w_k rows
    int fOff = which ? 128 : 0;
    float acc = 0.f;
    #pragma unroll 8
    for (int f = 0; f < 128; ++f)
        acc += pr[f] * Wk[(size_t)d * 256 + fOff + f];
    kpb[((size_t)which * PP + p) * 256 + d] = f2bf(acc);
}

// ---------------- fused 3-way projection with W-fragment REUSE
// Round-8 post-mortem: 1 KB ds_read per MFMA (zero reuse) caps MfmaUtil at
// ~10% (LDS ~85 B/cyc/CU). Now: wave = 32 X-rows (2 m-frags) x 64 N-cols
// (4 n-tiles of a W-QUARTER in 32 KB LDS); each wf read feeds 2 MFMAs ->
// 512 B/MFMA. Block = 512 thr = 8 waves = 256 rows. grid.x = (M/256)*4,
// bx = tile*4 + nq (adjacent quads share the X tile via L2/L3).
// Regs: acc 32 + X cur 16 + X prefetch 16 + xv 8 + addr ~15 (<128 cliff).
__global__ __launch_bounds__(512)
void proj_mfma(const float* __restrict__ Xq, const float* __restrict__ Xk,
               const float* __restrict__ Xv,
               const unsigned short* __restrict__ Wb,   // 768x256 bf16, q-rows pre-scaled
               const float* __restrict__ bias, float scaling,
               unsigned short* __restrict__ outq, unsigned short* __restrict__ outk,
               unsigned short* __restrict__ outv) {
    __shared__ unsigned short Wl[16384];   // 32 KB W-quarter, swizzled
    __shared__ float Lb[64];
    int which = blockIdx.y;
    int t = blockIdx.x >> 2, nq = blockIdx.x & 3;
    const float* X = (which == 0) ? Xq : ((which == 1) ? Xk : Xv);
    unsigned short* out = (which == 0) ? outq : ((which == 1) ? outk : outv);
    const unsigned short* wsrc = Wb + (size_t)which * 65536 + (size_t)nq * 16384;

    int tid = threadIdx.x, wid = tid >> 6, lane = tid & 63;
    int rgrp = lane & 15, kgrp = lane >> 4;

    // stage W-quarter: linear LDS dest, inverse-swizzled global source (rule #21)
    #pragma unroll
    for (int it = 0; it < 4; ++it) {
        int c = wid + it * 8;                 // chunk 0..31 (1 KB each)
        unsigned dst = (unsigned)c * 1024 + (unsigned)lane * 16;
        unsigned n = dst >> 9;                // local W row at this LDS slot
        unsigned gs = dst ^ ((n & 7) << 4);
        __builtin_amdgcn_global_load_lds((const char*)wsrc + gs,
                                         (char*)Wl + dst, 16, 0, 0);
    }
    if (tid < 64) Lb[tid] = bias[which * 256 + nq * 64 + tid] * ((which == 0) ? scaling : 1.0f);

    size_t row0 = (size_t)t * 256 + wid * 32 + rgrp;   // m-frag 0 row
    const float* xp0 = X + row0 * 256 + kgrp * 8;
    const float* xp1 = xp0 + 16 * 256;                 // m-frag 1 row
    float4 pa00 = *reinterpret_cast<const float4*>(xp0);
    float4 pa01 = *reinterpret_cast<const float4*>(xp0 + 4);
    float4 pa10 = *reinterpret_cast<const float4*>(xp1);
    float4 pa11 = *reinterpret_cast<const float4*>(xp1 + 4);
    __syncthreads();                          // drains W-stage + first X loads

    f32x4 acc[2][4];
    #pragma unroll
    for (int m = 0; m < 2; ++m)
        #pragma unroll
        for (int n = 0; n < 4; ++n) acc[m][n] = (f32x4){0.f, 0.f, 0.f, 0.f};

    unsigned lbase = ((unsigned)rgrp * 512 + (unsigned)kgrp * 16) ^ ((rgrp & 7) << 4);

    #pragma unroll
    for (int kk = 0; kk < 8; ++kk) {
        float4 c00 = pa00, c01 = pa01, c10 = pa10, c11 = pa11;
        if (kk < 7) {
            pa00 = *reinterpret_cast<const float4*>(xp0 + (kk + 1) * 32);
            pa01 = *reinterpret_cast<const float4*>(xp0 + (kk + 1) * 32 + 4);
            pa10 = *reinterpret_cast<const float4*>(xp1 + (kk + 1) * 32);
            pa11 = *reinterpret_cast<const float4*>(xp1 + (kk + 1) * 32 + 4);
        }
        bf16x8 x0, x1;
        x0[0] = (__bf16)c00.x; x0[1] = (__bf16)c00.y; x0[2] = (__bf16)c00.z; x0[3] = (__bf16)c00.w;
        x0[4] = (__bf16)c01.x; x0[5] = (__bf16)c01.y; x0[6] = (__bf16)c01.z; x0[7] = (__bf16)c01.w;
        x1[0] = (__bf16)c10.x; x1[1] = (__bf16)c10.y; x1[2] = (__bf16)c10.z; x1[3] = (__bf16)c10.w;
        x1[4] = (__bf16)c11.x; x1[5] = (__bf16)c11.y; x1[6] = (__bf16)c11.z; x1[7] = (__bf16)c11.w;
        unsigned kb = lbase ^ (unsigned)(kk * 64);
        #pragma unroll
        for (int nt = 0; nt < 4; ++nt) {
            bf16x8 wf = *reinterpret_cast<const bf16x8*>((const char*)Wl + kb + nt * 8192);
            acc[0][nt] = __builtin_amdgcn_mfma_f32_16x16x32_bf16(wf, x0, acc[0][nt], 0, 0, 0);
            acc[1][nt] = __builtin_amdgcn_mfma_f32_16x16x32_bf16(wf, x1, acc[1][nt], 0, 0, 0);
        }
    }

    // epilogue: lane stores rows row0 / row0+16, cols nq*64 + nt*16 + kgrp*4 ..+3
    #pragma unroll
    for (int mf = 0; mf < 2; ++mf) {
        size_t xrow = row0 + mf * 16;
        #pragma unroll
        for (int nt = 0; nt < 4; ++nt) {
            float4 bv = *reinterpret_cast<const float4*>(&Lb[nt * 16 + kgrp * 4]);
            ushort4 pk;
            pk.x = f2bf(acc[mf][nt][0] + bv.x);
            pk.y = f2bf(acc[mf][nt][1] + bv.y);
            pk.z = f2bf(acc[mf][nt][2] + bv.z);
            pk.w = f2bf(acc[mf][nt][3] + bv.w);
            *reinterpret_cast<ushort4*>(&out[xrow * 256 + nq * 64 + nt * 16 + kgrp * 4]) = pk;
        }
    }
}

// ---------------- output projection, same reuse structure (bf16 A, fp32 out)
__global__ __launch_bounds__(512)
void out_mfma(const unsigned short* __restrict__ Xb, const unsigned short* __restrict__ Wb,
              const float* __restrict__ bias, float* __restrict__ out) {
    __shared__ unsigned short Wl[16384];   // 32 KB, swizzled
    __shared__ float Lb[64];
    int t = blockIdx.x >> 2, nq = blockIdx.x & 3;
    const unsigned short* wsrc = Wb + (size_t)nq * 16384;
    int tid = threadIdx.x, wid = tid >> 6, lane = tid & 63;
    int rgrp = lane & 15, kgrp = lane >> 4;

    #pragma unroll
    for (int it = 0; it < 4; ++it) {
        int c = wid + it * 8;
        unsigned dst = (unsigned)c * 1024 + (unsigned)lane * 16;
        unsigned n = dst >> 9;
        unsigned gs = dst ^ ((n & 7) << 4);
        __builtin_amdgcn_global_load_lds((const char*)wsrc + gs,
                                         (char*)Wl + dst, 16, 0, 0);
    }
    if (tid < 64) Lb[tid] = bias[nq * 64 + tid];

    size_t row0 = (size_t)t * 256 + wid * 32 + rgrp;
    const unsigned short* xp0 = Xb + row0 * 256 + kgrp * 8;
    const unsigned short* xp1 = xp0 + 16 * 256;
    bf16x8 p0 = *reinterpret_cast<const bf16x8*>(xp0);
    bf16x8 p1 = *reinterpret_cast<const bf16x8*>(xp1);
    __syncthreads();

    f32x4 acc[2][4];
    #pragma unroll
    for (int m = 0; m < 2; ++m)
        #pragma unroll
        for (int n = 0; n < 4; ++n) acc[m][n] = (f32x4){0.f, 0.f, 0.f, 0.f};

    unsigned lbase = ((unsigned)rgrp * 512 + (unsigned)kgrp * 16) ^ ((rgrp & 7) << 4);

    #pragma unroll
    for (int kk = 0; kk < 8; ++kk) {
        bf16x8 a0 = p0, a1 = p1;
        if (kk < 7) {
            p0 = *reinterpret_cast<const bf16x8*>(xp0 + (kk + 1) * 32);
            p1 = *reinterpret_cast<const bf16x8*>(xp1 + (kk + 1) * 32);
        }
        unsigned kb = lbase ^ (unsigned)(kk * 64);
        #pragma unroll
        for (int nt = 0; nt < 4; ++nt) {
            bf16x8 wf = *reinterpret_cast<const bf16x8*>((const char*)Wl + kb + nt * 8192);
            acc[0][nt] = __builtin_amdgcn_mfma_f32_16x16x32_bf16(wf, a0, acc[0][nt], 0, 0, 0);
            acc[1][nt] = __builtin_amdgcn_mfma_f32_16x16x32_bf16(wf, a1, acc[1][nt], 0, 0, 0);
        }
    }

    #pragma unroll
    for (int mf = 0; mf < 2; ++mf) {
        size_t xrow = row0 + mf * 16;
        #pragma unroll
        for (int nt = 0; nt < 4; ++nt) {
            float4 bv = *reinterpret_cast<const float4*>(&Lb[nt * 16 + kgrp * 4]);
            float4 o;
            o.x = acc[mf][nt][0] + bv.x;
            o.y = acc[mf][nt][1] + bv.y;
            o.z = acc[mf][nt][2] + bv.z;
            o.w = acc[mf][nt][3] + bv.w;
            *reinterpret_cast<float4*>(&out[xrow * 256 + nq * 64 + nt * 16 + kgrp * 4]) = o;
        }
    }
}

// ---------------- MFMA fused attention: one (b,h) per 4-wave block (unchanged)
__global__ __launch_bounds__(256)
void attn_mfma(const unsigned short* __restrict__ qbuf,
               const unsigned short* __restrict__ kbuf,
               const unsigned short* __restrict__ vbuf,
               const unsigned short* __restrict__ kpb,
               const unsigned char* __restrict__ mask,
               unsigned short* __restrict__ ctx,
               int B) {
    __shared__ unsigned short Kp[96][40];      // K'(rows: 0..63 K, 64..79 kpy, 80..95 kpx)
    __shared__ unsigned short Pt[64][72];      // P bf16, rows l, cols s (49..63 zero)
    __shared__ unsigned short Vt[32][72];      // V^T: [d][s], cols 49..63 zeroed
    __shared__ unsigned short postab[49][40];  // [l][0..15]=posy(p=13+c), [l][20..35]=posx
    __shared__ int yy[L_Q], xx[L_Q];
    __shared__ unsigned char mb[52];

    int b = blockIdx.x, h = blockIdx.y;
    int tid = threadIdx.x, wid = tid >> 6, lane = tid & 63;
    int rgrp = lane & 15, kgrp = lane >> 4;
    size_t lstride = (size_t)B * D_MODEL;
    size_t base = (size_t)b * D_MODEL + (size_t)h * DK;

    // ---- phase 0: cooperative staging
    if (tid < L_Q) mb[tid] = mask[(size_t)b * L_Q + tid];
    if (tid < 196) {                      // V: l = tid>>2, 8 cols each -> transpose
        int l = tid >> 2, c = tid & 3;
        u16x8 vv = *reinterpret_cast<const u16x8*>(vbuf + (size_t)l * lstride + base + c * 8);
        #pragma unroll
        for (int j = 0; j < 8; ++j) Vt[c * 8 + j][l] = vv[j];
    }
    for (int e = tid; e < 512; e += 256) { // zero Vt cols 49..63
        int d = e >> 4, s2 = 48 + (e & 15);
        if (s2 > 48) Vt[d][s2] = 0;
    }
    for (int t = tid; t < 384; t += 256) { // K' staging: 96 rows x 4 chunks
        int r = t >> 2, kc = t & 3;
        const unsigned short* src;
        if (r < 64) {
            int kr = min(r, 48);
            src = kbuf + (size_t)kr * lstride + base + kc * 8;
        } else if (r < 80) {
            int p = r - 64 + 13;
            src = kpb + (size_t)p * D_MODEL + h * DK + kc * 8;
        } else {
            int p = r - 80 + 13;
            src = kpb + (size_t)(PP + p) * D_MODEL + h * DK + kc * 8;
        }
        *reinterpret_cast<u16x8*>(&Kp[r][kc * 8]) = *reinterpret_cast<const u16x8*>(src);
    }
    __syncthreads();
    if (tid < L_Q) {
        int r = tid / 7, c = tid % 7;
        int sy = 0, sx = 0;
        for (int rr = 0; rr <= r; ++rr) sy += (mb[rr * 7 + c] == 0);
        for (int cc = 0; cc <= c; ++cc) sx += (mb[r * 7 + cc] == 0);
        yy[tid] = sy; xx[tid] = sx;
    }
    __syncthreads();

    // ---- phase 1: S_full = Q . K'^T  (6 MFMAs, wave w = row tile w)
    int qrow = min(16 * wid + rgrp, 48);
    bf16x8 qfrag = *reinterpret_cast<const bf16x8*>(qbuf + (size_t)qrow * lstride + base + kgrp * 8);
    f32x4 acc[6];
    #pragma unroll
    for (int t = 0; t < 6; ++t) {
        bf16x8 bfrag = *reinterpret_cast<const bf16x8*>(&Kp[t * 16 + rgrp][kgrp * 8]);
        acc[t] = __builtin_amdgcn_mfma_f32_16x16x32_bf16(qfrag, bfrag,
                    (f32x4){0.f, 0.f, 0.f, 0.f}, 0, 0, 0);
    }

    // ---- phase 2: spill pos tiles (own rows only), assemble, softmax, write P
    #pragma unroll
    for (int i = 0; i < 4; ++i) {
        int l = 16 * wid + kgrp * 4 + i;
        if (l <= 48) {
            postab[l][rgrp]      = f2bf(acc[4][i]);
            postab[l][20 + rgrp] = f2bf(acc[5][i]);
        }
    }
    asm volatile("s_waitcnt lgkmcnt(0)" ::: "memory");

    #pragma unroll
    for (int i = 0; i < 4; ++i) {
        int l = 16 * wid + kgrp * 4 + i;
        int lc = min(l, 48);
        int yyl = yy[lc], xxl = xx[lc];
        float v[4];
        #pragma unroll
        for (int ct = 0; ct < 4; ++ct) {
            int s = ct * 16 + rgrp;
            int sc = min(s, 48);
            int iy = yyl - yy[sc] + (POS_OFF - 13);   // 0..14
            int ix = xxl - xx[sc] + (POS_OFF - 13);
            float val = acc[ct][i] + bf2f(postab[lc][iy]) + bf2f(postab[lc][20 + ix]);
            v[ct] = (s >= L_Q || mb[sc]) ? -1e30f : val;
        }
        float m = fmaxf(fmaxf(v[0], v[1]), fmaxf(v[2], v[3]));
        m = fmaxf(m, __shfl_xor(m, 1));
        m = fmaxf(m, __shfl_xor(m, 2));
        m = fmaxf(m, __shfl_xor(m, 4));
        m = fmaxf(m, __shfl_xor(m, 8));
        float ssum = 0.f, ex[4];
        #pragma unroll
        for (int ct = 0; ct < 4; ++ct) { ex[ct] = __expf(v[ct] - m); ssum += ex[ct]; }
        ssum += __shfl_xor(ssum, 1);
        ssum += __shfl_xor(ssum, 2);
        ssum += __shfl_xor(ssum, 4);
        ssum += __shfl_xor(ssum, 8);
        float is = 1.f / ssum;
        #pragma unroll
        for (int ct = 0; ct < 4; ++ct)
            Pt[l & 63][ct * 16 + rgrp] = f2bf(ex[ct] * is);
    }
    asm volatile("s_waitcnt lgkmcnt(0)" ::: "memory");

    // ---- phase 3: PV (4 MFMAs) + store
    f32x4 oacc[2];
    oacc[0] = (f32x4){0.f, 0.f, 0.f, 0.f};
    oacc[1] = (f32x4){0.f, 0.f, 0.f, 0.f};
    #pragma unroll
    for (int kc = 0; kc < 2; ++kc) {
        bf16x8 pa = *reinterpret_cast<const bf16x8*>(&Pt[16 * wid + rgrp][kc * 32 + kgrp * 8]);
        #pragma unroll
        for (int dt = 0; dt < 2; ++dt) {
            bf16x8 vb = *reinterpret_cast<const bf16x8*>(&Vt[dt * 16 + rgrp][kc * 32 + kgrp * 8]);
            oacc[dt] = __builtin_amdgcn_mfma_f32_16x16x32_bf16(pa, vb, oacc[dt], 0, 0, 0);
        }
    }
    #pragma unroll
    for (int dt = 0; dt < 2; ++dt)
        #pragma unroll
        for (int i = 0; i < 4; ++i) {
            int l = 16 * wid + kgrp * 4 + i;
            if (l <= 48)
                ctx[(size_t)l * lstride + base + dt * 16 + rgrp] = f2bf(oacc[dt][i]);
        }
}

extern "C" void kernel_launch(void* const* d_in, const int* in_sizes, int n_in,
                              void* d_out, int out_size, void* d_ws, size_t ws_size,
                              hipStream_t stream) {
    const float* query = (const float*)d_in[0];
    const float* key   = (const float*)d_in[1];
    const float* value = (const float*)d_in[2];
    const unsigned char* maskp = (const unsigned char*)d_in[3];
    const float* W     = (const float*)d_in[4];   // (768,256)
    const float* bias  = (const float*)d_in[5];   // (768,)
    const float* out_w = (const float*)d_in[6];   // (256,256)
    const float* out_b = (const float*)d_in[7];   // (256,)
    const float* pos_x = (const float*)d_in[8];   // (41,128)
    const float* pos_y = (const float*)d_in[9];   // (41,128)
    float* out = (float*)d_out;

    int B = in_sizes[0] / (L_Q * D_MODEL);        // 2048
    int M = L_Q * B;                              // 100352 = 392 * 256

    size_t nqkv = (size_t)M * D_MODEL;
    unsigned short* qb = (unsigned short*)d_ws;
    unsigned short* kb = qb + nqkv;
    unsigned short* vb = kb + nqkv;
    unsigned short* kpb = vb + nqkv;              // [2][41][256] bf16
    unsigned short* wbf = kpb + 2 * PP * D_MODEL; // 768x256 bf16 (q-rows pre-scaled)
    unsigned short* owbf = wbf + 768 * 256;       // 256x256 bf16

    const float scaling = 0.17677669529663687f;   // 1/sqrt(32)

    convert_w<<<256, 256, 0, stream>>>(W, out_w, scaling, wbf, owbf);
    prep_kpos<<<dim3(PP, 2), 256, 0, stream>>>(pos_y, pos_x, W, kpb);

    int gblocks = (M / 256) * 4;                  // 1568: bx = tile*4 + nq
    proj_mfma<<<dim3(gblocks, 3), 512, 0, stream>>>(query, key, value, wbf, bias, scaling,
                                                    qb, kb, vb);

    attn_mfma<<<dim3(B, NHEAD), 256, 0, stream>>>(qb, kb, vb, kpb, maskp, qb, B);

    out_mfma<<<gblocks, 512, 0, stream>>>(qb, owbf, out_b, out);
}

// Round 10
// 272.280 us; speedup vs baseline: 1.4131x; 1.4131x over previous
//
#include <hip/hip_runtime.h>
#include <hip/hip_bf16.h>

#define L_Q 49
#define D_MODEL 256
#define NHEAD 8
#define DK 32
#define PP 41
#define POS_OFF 20

typedef __attribute__((ext_vector_type(8))) __bf16 bf16x8;
typedef __attribute__((ext_vector_type(4))) float f32x4;
typedef __attribute__((ext_vector_type(8))) unsigned short u16x8;

__device__ __forceinline__ float bf2f(unsigned short u) {
    return __uint_as_float(((unsigned)u) << 16);
}
__device__ __forceinline__ unsigned short f2bf(float f) {
    unsigned u = __float_as_uint(f);
    return (unsigned short)((u + 0x7FFF + ((u >> 16) & 1)) >> 16);
}

// ---------------- one-time W conversion to bf16 (q-rows pre-scaled by `scaling`)
__global__ __launch_bounds__(256)
void convert_w(const float* __restrict__ W, const float* __restrict__ out_w,
               float scaling,
               unsigned short* __restrict__ wbf, unsigned short* __restrict__ owbf) {
    int i = blockIdx.x * 256 + threadIdx.x;   // 65536 float4 total
    if (i < 49152) {
        int row = i >> 6;                      // 64 float4 per 256-wide row
        float sc = (row < 256) ? scaling : 1.0f;
        float4 v = reinterpret_cast<const float4*>(W)[i];
        ushort4 o = { f2bf(v.x * sc), f2bf(v.y * sc), f2bf(v.z * sc), f2bf(v.w * sc) };
        reinterpret_cast<ushort4*>(wbf)[i] = o;
    } else {
        float4 v = reinterpret_cast<const float4*>(out_w)[i - 49152];
        ushort4 o = { f2bf(v.x), f2bf(v.y), f2bf(v.z), f2bf(v.w) };
        reinterpret_cast<ushort4*>(owbf)[i - 49152] = o;
    }
}

// ---------------- k_pos prep (f32 accumulate, bf16 store): kpb[which][p][d]
__global__ __launch_bounds__(256)
void prep_kpos(const float* __restrict__ pos_y, const float* __restrict__ pos_x,
               const float* __restrict__ W, unsigned short* __restrict__ kpb) {
    int p = blockIdx.x;          // 0..40
    int which = blockIdx.y;      // 0=y, 1=x
    __shared__ float pr[128];
    int d = threadIdx.x;         // 0..255
    if (d < 128) pr[d] = which ? pos_x[p * 128 + d] : pos_y[p * 128 + d];
    __syncthreads();
    const float* Wk = W + 256 * 256;  // w_k rows
    int fOff = which ? 128 : 0;
    float acc = 0.f;
    #pragma unroll 8
    for (int f = 0; f < 128; ++f)
        acc += pr[f] * Wk[(size_t)d * 256 + fOff + f];
    kpb[((size_t)which * PP + p) * 256 + d] = f2bf(acc);
}

// ---------------- fused 3-way projection: X-in-registers, W-quarters through LDS
// Round-9 post-mortem: N-split blocks on different XCDs re-fetched X from HBM
// (FETCH 303->604 MB). Now each block owns 256 rows EXCLUSIVELY (X read once);
// each wave holds 32 rows as bf16 in regs (xa[2][8] = 64 VGPR); the 4 W-quarters
// (32 KB each) rotate through LDS from L2 (W is L2-resident, ~free).
// LDS/MFMA = 512 B (4 ds_read feed 8 MFMAs) at 2 blocks/CU (16 waves).
// Regs: xa 64 + acc 32 (reused per quarter) + addr ~20 < 128 cliff.
__global__ __launch_bounds__(512)
void proj_mfma(const float* __restrict__ Xq, const float* __restrict__ Xk,
               const float* __restrict__ Xv,
               const unsigned short* __restrict__ Wb,   // 768x256 bf16, q-rows pre-scaled
               const float* __restrict__ bias, float scaling,
               unsigned short* __restrict__ outq, unsigned short* __restrict__ outk,
               unsigned short* __restrict__ outv) {
    __shared__ unsigned short Wl[16384];   // 32 KB W-quarter, swizzled
    __shared__ float Lb[256];
    int which = blockIdx.y;
    int t = blockIdx.x;
    const float* X = (which == 0) ? Xq : ((which == 1) ? Xk : Xv);
    unsigned short* out = (which == 0) ? outq : ((which == 1) ? outk : outv);
    const char* wsrc = (const char*)(Wb + (size_t)which * 65536);

    int tid = threadIdx.x, wid = tid >> 6, lane = tid & 63;
    int rgrp = lane & 15, kgrp = lane >> 4;

    if (tid < 256) Lb[tid] = bias[which * 256 + tid] * ((which == 0) ? scaling : 1.0f);

    // load the wave's 32 X-rows into registers as bf16 (X read exactly once)
    size_t row0 = (size_t)t * 256 + wid * 32 + rgrp;   // m-frag 0 row
    const float* xp0 = X + row0 * 256 + kgrp * 8;
    const float* xp1 = xp0 + 16 * 256;                 // m-frag 1 row
    bf16x8 xa[2][8];
    #pragma unroll
    for (int kk = 0; kk < 8; ++kk) {
        float4 a0 = *reinterpret_cast<const float4*>(xp0 + kk * 32);
        float4 a1 = *reinterpret_cast<const float4*>(xp0 + kk * 32 + 4);
        float4 b0 = *reinterpret_cast<const float4*>(xp1 + kk * 32);
        float4 b1 = *reinterpret_cast<const float4*>(xp1 + kk * 32 + 4);
        xa[0][kk][0] = (__bf16)a0.x; xa[0][kk][1] = (__bf16)a0.y;
        xa[0][kk][2] = (__bf16)a0.z; xa[0][kk][3] = (__bf16)a0.w;
        xa[0][kk][4] = (__bf16)a1.x; xa[0][kk][5] = (__bf16)a1.y;
        xa[0][kk][6] = (__bf16)a1.z; xa[0][kk][7] = (__bf16)a1.w;
        xa[1][kk][0] = (__bf16)b0.x; xa[1][kk][1] = (__bf16)b0.y;
        xa[1][kk][2] = (__bf16)b0.z; xa[1][kk][3] = (__bf16)b0.w;
        xa[1][kk][4] = (__bf16)b1.x; xa[1][kk][5] = (__bf16)b1.y;
        xa[1][kk][6] = (__bf16)b1.z; xa[1][kk][7] = (__bf16)b1.w;
    }

    unsigned lbase = ((unsigned)rgrp * 512 + (unsigned)kgrp * 16) ^ ((rgrp & 7) << 4);

    for (int nq = 0; nq < 4; ++nq) {
        if (nq) __syncthreads();              // all waves done reading prev quarter
        // stage W-quarter nq: linear LDS dest, inverse-swizzled source (rule #21)
        #pragma unroll
        for (int it = 0; it < 4; ++it) {
            int c = wid + it * 8;             // chunk 0..31 (1 KB each)
            unsigned dst = (unsigned)c * 1024 + (unsigned)lane * 16;
            unsigned n = dst >> 9;            // local W row at this LDS slot
            unsigned gs = dst ^ ((n & 7) << 4);
            __builtin_amdgcn_global_load_lds(wsrc + nq * 32768 + gs,
                                             (char*)Wl + dst, 16, 0, 0);
        }
        __syncthreads();                      // drains staging (and X loads, 1st iter)

        f32x4 acc[2][4];
        #pragma unroll
        for (int m = 0; m < 2; ++m)
            #pragma unroll
            for (int n = 0; n < 4; ++n) acc[m][n] = (f32x4){0.f, 0.f, 0.f, 0.f};

        #pragma unroll
        for (int kk = 0; kk < 8; ++kk) {
            unsigned kb = lbase ^ (unsigned)(kk * 64);
            #pragma unroll
            for (int nt = 0; nt < 4; ++nt) {
                bf16x8 wf = *reinterpret_cast<const bf16x8*>((const char*)Wl + kb + nt * 8192);
                acc[0][nt] = __builtin_amdgcn_mfma_f32_16x16x32_bf16(wf, xa[0][kk], acc[0][nt], 0, 0, 0);
                acc[1][nt] = __builtin_amdgcn_mfma_f32_16x16x32_bf16(wf, xa[1][kk], acc[1][nt], 0, 0, 0);
            }
        }

        // store this n-quarter: rows row0/row0+16, cols nq*64 + nt*16 + kgrp*4
        #pragma unroll
        for (int mf = 0; mf < 2; ++mf) {
            size_t xrow = row0 + mf * 16;
            #pragma unroll
            for (int nt = 0; nt < 4; ++nt) {
                float4 bv = *reinterpret_cast<const float4*>(&Lb[nq * 64 + nt * 16 + kgrp * 4]);
                ushort4 pk;
                pk.x = f2bf(acc[mf][nt][0] + bv.x);
                pk.y = f2bf(acc[mf][nt][1] + bv.y);
                pk.z = f2bf(acc[mf][nt][2] + bv.z);
                pk.w = f2bf(acc[mf][nt][3] + bv.w);
                *reinterpret_cast<ushort4*>(&out[xrow * 256 + nq * 64 + nt * 16 + kgrp * 4]) = pk;
            }
        }
    }
}

// ---------------- output projection, same X-in-regs structure (bf16 A, fp32 out)
__global__ __launch_bounds__(512)
void out_mfma(const unsigned short* __restrict__ Xb, const unsigned short* __restrict__ Wb,
              const float* __restrict__ bias, float* __restrict__ out) {
    __shared__ unsigned short Wl[16384];   // 32 KB, swizzled
    __shared__ float Lb[256];
    int t = blockIdx.x;
    int tid = threadIdx.x, wid = tid >> 6, lane = tid & 63;
    int rgrp = lane & 15, kgrp = lane >> 4;

    if (tid < 256) Lb[tid] = bias[tid];

    size_t row0 = (size_t)t * 256 + wid * 32 + rgrp;
    const unsigned short* xp0 = Xb + row0 * 256 + kgrp * 8;
    const unsigned short* xp1 = xp0 + 16 * 256;
    bf16x8 xa[2][8];
    #pragma unroll
    for (int kk = 0; kk < 8; ++kk) {
        xa[0][kk] = *reinterpret_cast<const bf16x8*>(xp0 + kk * 32);
        xa[1][kk] = *reinterpret_cast<const bf16x8*>(xp1 + kk * 32);
    }

    unsigned lbase = ((unsigned)rgrp * 512 + (unsigned)kgrp * 16) ^ ((rgrp & 7) << 4);

    for (int nq = 0; nq < 4; ++nq) {
        if (nq) __syncthreads();
        #pragma unroll
        for (int it = 0; it < 4; ++it) {
            int c = wid + it * 8;
            unsigned dst = (unsigned)c * 1024 + (unsigned)lane * 16;
            unsigned n = dst >> 9;
            unsigned gs = dst ^ ((n & 7) << 4);
            __builtin_amdgcn_global_load_lds((const char*)Wb + nq * 32768 + gs,
                                             (char*)Wl + dst, 16, 0, 0);
        }
        __syncthreads();

        f32x4 acc[2][4];
        #pragma unroll
        for (int m = 0; m < 2; ++m)
            #pragma unroll
            for (int n = 0; n < 4; ++n) acc[m][n] = (f32x4){0.f, 0.f, 0.f, 0.f};

        #pragma unroll
        for (int kk = 0; kk < 8; ++kk) {
            unsigned kb = lbase ^ (unsigned)(kk * 64);
            #pragma unroll
            for (int nt = 0; nt < 4; ++nt) {
                bf16x8 wf = *reinterpret_cast<const bf16x8*>((const char*)Wl + kb + nt * 8192);
                acc[0][nt] = __builtin_amdgcn_mfma_f32_16x16x32_bf16(wf, xa[0][kk], acc[0][nt], 0, 0, 0);
                acc[1][nt] = __builtin_amdgcn_mfma_f32_16x16x32_bf16(wf, xa[1][kk], acc[1][nt], 0, 0, 0);
            }
        }

        #pragma unroll
        for (int mf = 0; mf < 2; ++mf) {
            size_t xrow = row0 + mf * 16;
            #pragma unroll
            for (int nt = 0; nt < 4; ++nt) {
                float4 bv = *reinterpret_cast<const float4*>(&Lb[nq * 64 + nt * 16 + kgrp * 4]);
                float4 o;
                o.x = acc[mf][nt][0] + bv.x;
                o.y = acc[mf][nt][1] + bv.y;
                o.z = acc[mf][nt][2] + bv.z;
                o.w = acc[mf][nt][3] + bv.w;
                *reinterpret_cast<float4*>(&out[xrow * 256 + nq * 64 + nt * 16 + kgrp * 4]) = o;
            }
        }
    }
}

// ---------------- MFMA fused attention: one (b,h) per 4-wave block (unchanged)
__global__ __launch_bounds__(256)
void attn_mfma(const unsigned short* __restrict__ qbuf,
               const unsigned short* __restrict__ kbuf,
               const unsigned short* __restrict__ vbuf,
               const unsigned short* __restrict__ kpb,
               const unsigned char* __restrict__ mask,
               unsigned short* __restrict__ ctx,
               int B) {
    __shared__ unsigned short Kp[96][40];      // K'(rows: 0..63 K, 64..79 kpy, 80..95 kpx)
    __shared__ unsigned short Pt[64][72];      // P bf16, rows l, cols s (49..63 zero)
    __shared__ unsigned short Vt[32][72];      // V^T: [d][s], cols 49..63 zeroed
    __shared__ unsigned short postab[49][40];  // [l][0..15]=posy(p=13+c), [l][20..35]=posx
    __shared__ int yy[L_Q], xx[L_Q];
    __shared__ unsigned char mb[52];

    int b = blockIdx.x, h = blockIdx.y;
    int tid = threadIdx.x, wid = tid >> 6, lane = tid & 63;
    int rgrp = lane & 15, kgrp = lane >> 4;
    size_t lstride = (size_t)B * D_MODEL;
    size_t base = (size_t)b * D_MODEL + (size_t)h * DK;

    // ---- phase 0: cooperative staging
    if (tid < L_Q) mb[tid] = mask[(size_t)b * L_Q + tid];
    if (tid < 196) {                      // V: l = tid>>2, 8 cols each -> transpose
        int l = tid >> 2, c = tid & 3;
        u16x8 vv = *reinterpret_cast<const u16x8*>(vbuf + (size_t)l * lstride + base + c * 8);
        #pragma unroll
        for (int j = 0; j < 8; ++j) Vt[c * 8 + j][l] = vv[j];
    }
    for (int e = tid; e < 512; e += 256) { // zero Vt cols 49..63
        int d = e >> 4, s2 = 48 + (e & 15);
        if (s2 > 48) Vt[d][s2] = 0;
    }
    for (int t = tid; t < 384; t += 256) { // K' staging: 96 rows x 4 chunks
        int r = t >> 2, kc = t & 3;
        const unsigned short* src;
        if (r < 64) {
            int kr = min(r, 48);
            src = kbuf + (size_t)kr * lstride + base + kc * 8;
        } else if (r < 80) {
            int p = r - 64 + 13;
            src = kpb + (size_t)p * D_MODEL + h * DK + kc * 8;
        } else {
            int p = r - 80 + 13;
            src = kpb + (size_t)(PP + p) * D_MODEL + h * DK + kc * 8;
        }
        *reinterpret_cast<u16x8*>(&Kp[r][kc * 8]) = *reinterpret_cast<const u16x8*>(src);
    }
    __syncthreads();
    if (tid < L_Q) {
        int r = tid / 7, c = tid % 7;
        int sy = 0, sx = 0;
        for (int rr = 0; rr <= r; ++rr) sy += (mb[rr * 7 + c] == 0);
        for (int cc = 0; cc <= c; ++cc) sx += (mb[r * 7 + cc] == 0);
        yy[tid] = sy; xx[tid] = sx;
    }
    __syncthreads();

    // ---- phase 1: S_full = Q . K'^T  (6 MFMAs, wave w = row tile w)
    int qrow = min(16 * wid + rgrp, 48);
    bf16x8 qfrag = *reinterpret_cast<const bf16x8*>(qbuf + (size_t)qrow * lstride + base + kgrp * 8);
    f32x4 acc[6];
    #pragma unroll
    for (int t = 0; t < 6; ++t) {
        bf16x8 bfrag = *reinterpret_cast<const bf16x8*>(&Kp[t * 16 + rgrp][kgrp * 8]);
        acc[t] = __builtin_amdgcn_mfma_f32_16x16x32_bf16(qfrag, bfrag,
                    (f32x4){0.f, 0.f, 0.f, 0.f}, 0, 0, 0);
    }

    // ---- phase 2: spill pos tiles (own rows only), assemble, softmax, write P
    #pragma unroll
    for (int i = 0; i < 4; ++i) {
        int l = 16 * wid + kgrp * 4 + i;
        if (l <= 48) {
            postab[l][rgrp]      = f2bf(acc[4][i]);
            postab[l][20 + rgrp] = f2bf(acc[5][i]);
        }
    }
    asm volatile("s_waitcnt lgkmcnt(0)" ::: "memory");

    #pragma unroll
    for (int i = 0; i < 4; ++i) {
        int l = 16 * wid + kgrp * 4 + i;
        int lc = min(l, 48);
        int yyl = yy[lc], xxl = xx[lc];
        float v[4];
        #pragma unroll
        for (int ct = 0; ct < 4; ++ct) {
            int s = ct * 16 + rgrp;
            int sc = min(s, 48);
            int iy = yyl - yy[sc] + (POS_OFF - 13);   // 0..14
            int ix = xxl - xx[sc] + (POS_OFF - 13);
            float val = acc[ct][i] + bf2f(postab[lc][iy]) + bf2f(postab[lc][20 + ix]);
            v[ct] = (s >= L_Q || mb[sc]) ? -1e30f : val;
        }
        float m = fmaxf(fmaxf(v[0], v[1]), fmaxf(v[2], v[3]));
        m = fmaxf(m, __shfl_xor(m, 1));
        m = fmaxf(m, __shfl_xor(m, 2));
        m = fmaxf(m, __shfl_xor(m, 4));
        m = fmaxf(m, __shfl_xor(m, 8));
        float ssum = 0.f, ex[4];
        #pragma unroll
        for (int ct = 0; ct < 4; ++ct) { ex[ct] = __expf(v[ct] - m); ssum += ex[ct]; }
        ssum += __shfl_xor(ssum, 1);
        ssum += __shfl_xor(ssum, 2);
        ssum += __shfl_xor(ssum, 4);
        ssum += __shfl_xor(ssum, 8);
        float is = 1.f / ssum;
        #pragma unroll
        for (int ct = 0; ct < 4; ++ct)
            Pt[l & 63][ct * 16 + rgrp] = f2bf(ex[ct] * is);
    }
    asm volatile("s_waitcnt lgkmcnt(0)" ::: "memory");

    // ---- phase 3: PV (4 MFMAs) + store
    f32x4 oacc[2];
    oacc[0] = (f32x4){0.f, 0.f, 0.f, 0.f};
    oacc[1] = (f32x4){0.f, 0.f, 0.f, 0.f};
    #pragma unroll
    for (int kc = 0; kc < 2; ++kc) {
        bf16x8 pa = *reinterpret_cast<const bf16x8*>(&Pt[16 * wid + rgrp][kc * 32 + kgrp * 8]);
        #pragma unroll
        for (int dt = 0; dt < 2; ++dt) {
            bf16x8 vb = *reinterpret_cast<const bf16x8*>(&Vt[dt * 16 + rgrp][kc * 32 + kgrp * 8]);
            oacc[dt] = __builtin_amdgcn_mfma_f32_16x16x32_bf16(pa, vb, oacc[dt], 0, 0, 0);
        }
    }
    #pragma unroll
    for (int dt = 0; dt < 2; ++dt)
        #pragma unroll
        for (int i = 0; i < 4; ++i) {
            int l = 16 * wid + kgrp * 4 + i;
            if (l <= 48)
                ctx[(size_t)l * lstride + base + dt * 16 + rgrp] = f2bf(oacc[dt][i]);
        }
}

extern "C" void kernel_launch(void* const* d_in, const int* in_sizes, int n_in,
                              void* d_out, int out_size, void* d_ws, size_t ws_size,
                              hipStream_t stream) {
    const float* query = (const float*)d_in[0];
    const float* key   = (const float*)d_in[1];
    const float* value = (const float*)d_in[2];
    const unsigned char* maskp = (const unsigned char*)d_in[3];
    const float* W     = (const float*)d_in[4];   // (768,256)
    const float* bias  = (const float*)d_in[5];   // (768,)
    const float* out_w = (const float*)d_in[6];   // (256,256)
    const float* out_b = (const float*)d_in[7];   // (256,)
    const float* pos_x = (const float*)d_in[8];   // (41,128)
    const float* pos_y = (const float*)d_in[9];   // (41,128)
    float* out = (float*)d_out;

    int B = in_sizes[0] / (L_Q * D_MODEL);        // 2048
    int M = L_Q * B;                              // 100352 = 392 * 256

    size_t nqkv = (size_t)M * D_MODEL;
    unsigned short* qb = (unsigned short*)d_ws;
    unsigned short* kb = qb + nqkv;
    unsigned short* vb = kb + nqkv;
    unsigned short* kpb = vb + nqkv;              // [2][41][256] bf16
    unsigned short* wbf = kpb + 2 * PP * D_MODEL; // 768x256 bf16 (q-rows pre-scaled)
    unsigned short* owbf = wbf + 768 * 256;       // 256x256 bf16

    const float scaling = 0.17677669529663687f;   // 1/sqrt(32)

    convert_w<<<256, 256, 0, stream>>>(W, out_w, scaling, wbf, owbf);
    prep_kpos<<<dim3(PP, 2), 256, 0, stream>>>(pos_y, pos_x, W, kpb);

    int gblocks = M / 256;                        // 392 (each block owns its rows)
    proj_mfma<<<dim3(gblocks, 3), 512, 0, stream>>>(query, key, value, wbf, bias, scaling,
                                                    qb, kb, vb);

    attn_mfma<<<dim3(B, NHEAD), 256, 0, stream>>>(qb, kb, vb, kpb, maskp, qb, B);

    out_mfma<<<gblocks, 512, 0, stream>>>(qb, owbf, out_b, out);
}